// Round 20
// baseline (161.493 us; speedup 1.0000x reference)
//
#include <hip/hip_runtime.h>
#include <hip/hip_bf16.h>
#include <stdint.h>

#define N_TOK 8192
#define D_K   1024
#define NB    128            // block tile (BM=BN=128)
#define NT    16             // K-tiles of 64
#define GSTRIDE 32768        // bytes per 32-row group: 16 tiles x 64 lanes x 32B

typedef __attribute__((ext_vector_type(4)))  int   i32x4;
typedef __attribute__((ext_vector_type(8)))  int   i32x8;
typedef __attribute__((ext_vector_type(16))) float f32x16;

// fp32 -> OCP e4m3fn, RNE, with subnormal handling (inputs ~N(0,1)).
__device__ __forceinline__ unsigned int f32_to_e4m3(float x) {
  uint32_t u = __builtin_bit_cast(uint32_t, x);
  unsigned int s = (u >> 24) & 0x80u;
  float ax = __builtin_fabsf(x);
  if (ax < 0.015625f) {                    // < 2^-6: subnormal
    int q = (int)rintf(ax * 512.0f);       // 0..8 (8 -> 0x08 = 2^-6 exact)
    return s | (unsigned int)q;
  }
  uint32_t au = u & 0x7FFFFFFFu;
  uint32_t v = au + 0x7FFFFu + ((au >> 20) & 1u);   // RNE at 3 mantissa bits
  int em = (int)(v >> 20) - 960;           // rebias 127->7 (<<3)
  if (em > 0x7E) em = 0x7E;                // clamp to 448 (0x7F = NaN)
  return s | (unsigned int)em;
}

// LDS-staged permuting convert: block = (group g of 32 rows, array sel).
// Coalesced float4 reads -> fp8 scatter into 32KB LDS fragment image ->
// coalesced 16B stores. Fragment layout: A'[g][t][lane][32B], t = k>>6,
// lane = ((k>>5)&1)<<5 | (row&31), byte = k&31. Also zeroes out[0].
__global__ void __launch_bounds__(256)
convert_perm_kernel(const float* __restrict__ a, const float* __restrict__ b,
                    unsigned char* __restrict__ oa,
                    unsigned char* __restrict__ ob,
                    float* __restrict__ out) {
  __shared__ unsigned int P[8192];   // 32 KB
  const int blk = (int)blockIdx.x;   // 512 blocks
  if (blk == 0 && threadIdx.x == 0) out[0] = 0.0f;
  const int g   = blk >> 1;
  const float* __restrict__ src = (blk & 1) ? b : a;
  unsigned char* __restrict__ dst = (blk & 1) ? ob : oa;
  const int tid = threadIdx.x;

  const float4* s4 = (const float4*)src + (size_t)g * 8192;
  const int koff = (tid >> 4) * 512 + ((tid >> 3) & 1) * 256 + (tid & 7);
#pragma unroll
  for (int i = 0; i < 32; ++i) {
    float4 v = s4[i * 256 + tid];          // row i, k = tid*4 (coalesced)
    unsigned int w = f32_to_e4m3(v.x) | (f32_to_e4m3(v.y) << 8) |
                     (f32_to_e4m3(v.z) << 16) | (f32_to_e4m3(v.w) << 24);
    P[koff + i * 8] = w;
  }
  __syncthreads();
  i32x4* d4 = (i32x4*)(dst + (size_t)g * GSTRIDE);
  const i32x4* p4 = (const i32x4*)P;
#pragma unroll
  for (int i = 0; i < 8; ++i) d4[i * 256 + tid] = p4[i * 256 + tid];
}

// Fused 128x128-tile MX-fp8 GEMM + sigmoid-contrastive loss, LDS-free,
// 32x32x64 scaled MFMA. R19: epilogue with raw HW transcendentals
// (__builtin_amdgcn_exp2f/logf = 1 v_exp/v_log each vs libm sequences),
// 4 independent accumulator chains (S/p per ACC quadrant), single frag
// set (R17's dbuf was dead — compiler re-serialized it anyway).
__global__ void __launch_bounds__(256)
sigc_kernel(const unsigned char* __restrict__ A8,
            const unsigned char* __restrict__ B8,
            const int* __restrict__ labA, const int* __restrict__ labB,
            const float* __restrict__ scale_p, const float* __restrict__ bias_p,
            float* __restrict__ out) {
  __shared__ int sLabA[NB];
  __shared__ int sLabB[NB];
  __shared__ float sPart[4];

  const int tid  = threadIdx.x;
  const int lane = tid & 63;
  const int wid  = tid >> 6;      // 0..3
  const int wr   = wid >> 1;      // 0..1 (M half)
  const int wc   = wid & 1;       // 0..1 (N half)

  // 2-D XCD region mapping on the 64x64 block grid.
  const int bid = (int)blockIdx.x;
  const int xcd = bid & 7;
  const int ii  = bid >> 3;                    // 0..511
  const int rr  = (xcd >> 1) * 16 + (ii & 15); // 0..63
  const int cc  = (xcd & 1) * 32 + (ii >> 4);  // 0..63

  if (tid < 128)      sLabA[tid] = labA[rr * NB + tid];
  else                sLabB[tid - 128] = labB[cc * NB + (tid - 128)];

  // Fragment base pointers: frag (g,t) at (g*16+t)*2048 + lane*32.
  const unsigned char* aF0 = A8 + (size_t)(rr * 4 + wr * 2) * GSTRIDE + lane * 32;
  const unsigned char* aF1 = aF0 + GSTRIDE;
  const unsigned char* bF0 = B8 + (size_t)(cc * 4 + wc * 2) * GSTRIDE + lane * 32;
  const unsigned char* bF1 = bF0 + GSTRIDE;

  f32x16 acc00 = {0}, acc01 = {0}, acc10 = {0}, acc11 = {0};

#pragma unroll
  for (int t = 0; t < NT; ++t) {
    i32x8 fa0 = *(const i32x8*)(aF0 + t * 2048);
    i32x8 fa1 = *(const i32x8*)(aF1 + t * 2048);
    i32x8 fb0 = *(const i32x8*)(bF0 + t * 2048);
    i32x8 fb1 = *(const i32x8*)(bF1 + t * 2048);
    __builtin_amdgcn_s_setprio(1);
    acc00 = __builtin_amdgcn_mfma_scale_f32_32x32x64_f8f6f4(
        fa0, fb0, acc00, 0, 0, 0, 0x7F7F7F7F, 0, 0x7F7F7F7F);
    acc01 = __builtin_amdgcn_mfma_scale_f32_32x32x64_f8f6f4(
        fa0, fb1, acc01, 0, 0, 0, 0x7F7F7F7F, 0, 0x7F7F7F7F);
    acc10 = __builtin_amdgcn_mfma_scale_f32_32x32x64_f8f6f4(
        fa1, fb0, acc10, 0, 0, 0, 0x7F7F7F7F, 0, 0x7F7F7F7F);
    acc11 = __builtin_amdgcn_mfma_scale_f32_32x32x64_f8f6f4(
        fa1, fb1, acc11, 0, 0, 0, 0x7F7F7F7F, 0, 0x7F7F7F7F);
    __builtin_amdgcn_s_setprio(0);
  }

  __syncthreads();   // publish labels before epilogue

  // Epilogue: u = logit*log2e. Per element: S1 += u, S2 += |u|,
  // p = fma(p, 2^-|u|, p); matches: Sm += u. loss_lane =
  // 0.5*(S1+S2) - Sm + log2(PROD p); scaled by ln2/N at the end.
  // 32x32 C/D layout: col = lane&31, row = (reg&3)+8*(reg>>2)+4*(lane>>5).
  const float L2E = 1.4426950408889634f;
  const float sl2e = scale_p[0] * L2E;
  const float bl2e = bias_p[0] * L2E;
  const int colIn = lane & 31;
  const int hi32  = lane >> 5;
  const int colL0 = sLabB[wc * 64 + colIn];
  const int colL1 = sLabB[wc * 64 + 32 + colIn];
  int rl0[16], rl1[16];
#pragma unroll
  for (int r = 0; r < 16; ++r) {
    const int rbase = (r & 3) + 8 * (r >> 2) + 4 * hi32;
    rl0[r] = sLabA[wr * 64 + rbase];
    rl1[r] = sLabA[wr * 64 + 32 + rbase];
  }

  float S1a = 0.f, S2a = 0.f, Sma = 0.f, pa = 1.0f;
  float S1b = 0.f, S2b = 0.f, Smb = 0.f, pb = 1.0f;
  float S1c = 0.f, S2c = 0.f, Smc = 0.f, pc = 1.0f;
  float S1d = 0.f, S2d = 0.f, Smd = 0.f, pd = 1.0f;

#define EPI(ACC, RL, CL, S1x, S2x, Smx, px) do {                           \
    _Pragma("unroll") for (int _r = 0; _r < 16; ++_r) {                    \
      const float _u = fmaf(sl2e, ACC[_r], bl2e);                          \
      const float _au = fabsf(_u);                                         \
      S1x += _u;                                                           \
      S2x += _au;                                                          \
      px = fmaf(px, __builtin_amdgcn_exp2f(-_au), px);                     \
      Smx += (RL[_r] == (CL)) ? _u : 0.0f;                                 \
    } } while (0)

  EPI(acc00, rl0, colL0, S1a, S2a, Sma, pa);
  EPI(acc01, rl0, colL1, S1b, S2b, Smb, pb);
  EPI(acc10, rl1, colL0, S1c, S2c, Smc, pc);
  EPI(acc11, rl1, colL1, S1d, S2d, Smd, pd);

  const float S1 = (S1a + S1b) + (S1c + S1d);
  const float S2 = (S2a + S2b) + (S2c + S2d);
  const float Sm = (Sma + Smb) + (Smc + Smd);
  const float pp = (pa * pb) * (pc * pd);         // <= 2^64, in range
  float loss = 0.5f * (S1 + S2) - Sm + __builtin_amdgcn_logf(pp);

#pragma unroll
  for (int off = 32; off > 0; off >>= 1) loss += __shfl_down(loss, off, 64);
  if (lane == 0) sPart[wid] = loss;
  __syncthreads();
  if (tid == 0) {
    const float s = (sPart[0] + sPart[1]) + (sPart[2] + sPart[3]);
    atomicAdd(out, s * (0.6931471805599453f / (float)N_TOK));
  }
}

extern "C" void kernel_launch(void* const* d_in, const int* in_sizes, int n_in,
                              void* d_out, int out_size, void* d_ws, size_t ws_size,
                              hipStream_t stream) {
  const float* a  = (const float*)d_in[0];
  const float* b  = (const float*)d_in[1];
  const int*   la = (const int*)d_in[2];
  const int*   lb = (const int*)d_in[3];
  const float* sc = (const float*)d_in[4];
  const float* bi = (const float*)d_in[5];
  float* out = (float*)d_out;

  unsigned char* wa = (unsigned char*)d_ws;          // fp8 A', 8 MB
  unsigned char* wb = wa + (size_t)N_TOK * D_K;      // fp8 B', 8 MB

  convert_perm_kernel<<<512, 256, 0, stream>>>(a, b, wa, wb, out);
  const int grid = (N_TOK / NB) * (N_TOK / NB);      // 4096
  sigc_kernel<<<grid, 256, 0, stream>>>(wa, wb, la, lb, sc, bi, out);
}

// Round 21
// 100.289 us; speedup vs baseline: 1.6103x; 1.6103x over previous
//
#include <hip/hip_runtime.h>
#include <hip/hip_bf16.h>
#include <stdint.h>

#define N_TOK 8192
#define D_K   1024
#define NB    128            // block tile (BM=BN=128)
#define NT    16             // K-tiles of 64
#define GSTRIDE 32768        // bytes per 32-row group: 16 tiles x 64 lanes x 32B

typedef __attribute__((ext_vector_type(4)))  int   i32x4;
typedef __attribute__((ext_vector_type(8)))  int   i32x8;
typedef __attribute__((ext_vector_type(16))) float f32x16;

// fp32 -> OCP e4m3fn, RNE, with subnormal handling (inputs ~N(0,1)).
__device__ __forceinline__ unsigned int f32_to_e4m3(float x) {
  uint32_t u = __builtin_bit_cast(uint32_t, x);
  unsigned int s = (u >> 24) & 0x80u;
  float ax = __builtin_fabsf(x);
  if (ax < 0.015625f) {                    // < 2^-6: subnormal
    int q = (int)rintf(ax * 512.0f);       // 0..8 (8 -> 0x08 = 2^-6 exact)
    return s | (unsigned int)q;
  }
  uint32_t au = u & 0x7FFFFFFFu;
  uint32_t v = au + 0x7FFFFu + ((au >> 20) & 1u);   // RNE at 3 mantissa bits
  int em = (int)(v >> 20) - 960;           // rebias 127->7 (<<3)
  if (em > 0x7E) em = 0x7E;                // clamp to 448 (0x7F = NaN)
  return s | (unsigned int)em;
}

// LDS-staged permuting convert: block = (group g of 32 rows, array sel).
// Coalesced float4 reads -> fp8 scatter into 32KB LDS fragment image ->
// coalesced 16B stores. Fragment layout: A'[g][t][lane][32B], t = k>>6,
// lane = ((k>>5)&1)<<5 | (row&31), byte = k&31. Also zeroes out[0].
__global__ void __launch_bounds__(256)
convert_perm_kernel(const float* __restrict__ a, const float* __restrict__ b,
                    unsigned char* __restrict__ oa,
                    unsigned char* __restrict__ ob,
                    float* __restrict__ out) {
  __shared__ unsigned int P[8192];   // 32 KB
  const int blk = (int)blockIdx.x;   // 512 blocks
  if (blk == 0 && threadIdx.x == 0) out[0] = 0.0f;
  const int g   = blk >> 1;
  const float* __restrict__ src = (blk & 1) ? b : a;
  unsigned char* __restrict__ dst = (blk & 1) ? ob : oa;
  const int tid = threadIdx.x;

  const float4* s4 = (const float4*)src + (size_t)g * 8192;
  const int koff = (tid >> 4) * 512 + ((tid >> 3) & 1) * 256 + (tid & 7);
#pragma unroll
  for (int i = 0; i < 32; ++i) {
    float4 v = s4[i * 256 + tid];          // row i, k = tid*4 (coalesced)
    unsigned int w = f32_to_e4m3(v.x) | (f32_to_e4m3(v.y) << 8) |
                     (f32_to_e4m3(v.z) << 16) | (f32_to_e4m3(v.w) << 24);
    P[koff + i * 8] = w;
  }
  __syncthreads();
  i32x4* d4 = (i32x4*)(dst + (size_t)g * GSTRIDE);
  const i32x4* p4 = (const i32x4*)P;
#pragma unroll
  for (int i = 0; i < 8; ++i) d4[i * 256 + tid] = p4[i * 256 + tid];
}

// Fused 128x128-tile MX-fp8 GEMM + sigmoid-contrastive loss, LDS-free,
// 32x32x64 scaled MFMA. R20 = R18's exact loop structure (explicit
// LOADT/MMAT register dbuf — 84 VGPR, 28% occupancy, no compiler
// software-pipelining bloat) + R19's cheap epilogue (4 independent
// chains, raw v_exp/v_log transcendentals). R19's single-frag full
// unroll let the compiler hoist loads -> 224 VGPR -> 10% occupancy.
__global__ void __launch_bounds__(256)
sigc_kernel(const unsigned char* __restrict__ A8,
            const unsigned char* __restrict__ B8,
            const int* __restrict__ labA, const int* __restrict__ labB,
            const float* __restrict__ scale_p, const float* __restrict__ bias_p,
            float* __restrict__ out) {
  __shared__ int sLabA[NB];
  __shared__ int sLabB[NB];
  __shared__ float sPart[4];

  const int tid  = threadIdx.x;
  const int lane = tid & 63;
  const int wid  = tid >> 6;      // 0..3
  const int wr   = wid >> 1;      // 0..1 (M half)
  const int wc   = wid & 1;       // 0..1 (N half)

  // 2-D XCD region mapping on the 64x64 block grid.
  const int bid = (int)blockIdx.x;
  const int xcd = bid & 7;
  const int ii  = bid >> 3;                    // 0..511
  const int rr  = (xcd >> 1) * 16 + (ii & 15); // 0..63
  const int cc  = (xcd & 1) * 32 + (ii >> 4);  // 0..63

  if (tid < 128)      sLabA[tid] = labA[rr * NB + tid];
  else                sLabB[tid - 128] = labB[cc * NB + (tid - 128)];

  // Fragment base pointers: frag (g,t) at (g*16+t)*2048 + lane*32.
  const unsigned char* aF[2];
  const unsigned char* bF[2];
#pragma unroll
  for (int f = 0; f < 2; ++f) {
    aF[f] = A8 + (size_t)(rr * 4 + wr * 2 + f) * GSTRIDE + lane * 32;
    bF[f] = B8 + (size_t)(cc * 4 + wc * 2 + f) * GSTRIDE + lane * 32;
  }

#define LOADT(fa, fb, T) do {                                              \
    fa[0] = *(const i32x8*)(aF[0] + (T) * 2048);                           \
    fa[1] = *(const i32x8*)(aF[1] + (T) * 2048);                           \
    fb[0] = *(const i32x8*)(bF[0] + (T) * 2048);                           \
    fb[1] = *(const i32x8*)(bF[1] + (T) * 2048);                           \
  } while (0)

#define MMAT(fa, fb) do {                                                  \
    __builtin_amdgcn_s_setprio(1);                                         \
    acc00 = __builtin_amdgcn_mfma_scale_f32_32x32x64_f8f6f4(               \
        fa[0], fb[0], acc00, 0, 0, 0, 0x7F7F7F7F, 0, 0x7F7F7F7F);          \
    acc01 = __builtin_amdgcn_mfma_scale_f32_32x32x64_f8f6f4(               \
        fa[0], fb[1], acc01, 0, 0, 0, 0x7F7F7F7F, 0, 0x7F7F7F7F);          \
    acc10 = __builtin_amdgcn_mfma_scale_f32_32x32x64_f8f6f4(               \
        fa[1], fb[0], acc10, 0, 0, 0, 0x7F7F7F7F, 0, 0x7F7F7F7F);          \
    acc11 = __builtin_amdgcn_mfma_scale_f32_32x32x64_f8f6f4(               \
        fa[1], fb[1], acc11, 0, 0, 0, 0x7F7F7F7F, 0, 0x7F7F7F7F);          \
    __builtin_amdgcn_s_setprio(0); } while (0)

  f32x16 acc00 = {0}, acc01 = {0}, acc10 = {0}, acc11 = {0};

  i32x8 fA0[2], fB0[2], fA1[2], fB1[2];

  // Prologue: tile 0 fragments.
  LOADT(fA0, fB0, 0);

#pragma unroll
  for (int t2 = 0; t2 < NT / 2; ++t2) {
    const int e = 2 * t2;
    LOADT(fA1, fB1, e + 1);     // odd-tile loads fly under even MFMA
    MMAT(fA0, fB0);
    if (t2 < NT / 2 - 1) LOADT(fA0, fB0, e + 2);
    MMAT(fA1, fB1);
  }

  __syncthreads();   // publish labels before epilogue

  // Epilogue: u = logit*log2e. Per element: S1 += u, S2 += |u|,
  // p = fma(p, 2^-|u|, p); matches: Sm += u. loss_lane =
  // 0.5*(S1+S2) - Sm + log2(PROD p); scaled by ln2/N at the end.
  // 32x32 C/D layout: col = lane&31, row = (reg&3)+8*(reg>>2)+4*(lane>>5).
  const float L2E = 1.4426950408889634f;
  const float sl2e = scale_p[0] * L2E;
  const float bl2e = bias_p[0] * L2E;
  const int colIn = lane & 31;
  const int hi32  = lane >> 5;
  const int colL0 = sLabB[wc * 64 + colIn];
  const int colL1 = sLabB[wc * 64 + 32 + colIn];
  int rl0[16], rl1[16];
#pragma unroll
  for (int r = 0; r < 16; ++r) {
    const int rbase = (r & 3) + 8 * (r >> 2) + 4 * hi32;
    rl0[r] = sLabA[wr * 64 + rbase];
    rl1[r] = sLabA[wr * 64 + 32 + rbase];
  }

  float S1a = 0.f, S2a = 0.f, Sma = 0.f, pa = 1.0f;
  float S1b = 0.f, S2b = 0.f, Smb = 0.f, pb = 1.0f;
  float S1c = 0.f, S2c = 0.f, Smc = 0.f, pc = 1.0f;
  float S1d = 0.f, S2d = 0.f, Smd = 0.f, pd = 1.0f;

#define EPI(ACC, RL, CL, S1x, S2x, Smx, px) do {                           \
    _Pragma("unroll") for (int _r = 0; _r < 16; ++_r) {                    \
      const float _u = fmaf(sl2e, ACC[_r], bl2e);                          \
      const float _au = fabsf(_u);                                         \
      S1x += _u;                                                           \
      S2x += _au;                                                          \
      px = fmaf(px, __builtin_amdgcn_exp2f(-_au), px);                     \
      Smx += (RL[_r] == (CL)) ? _u : 0.0f;                                 \
    } } while (0)

  EPI(acc00, rl0, colL0, S1a, S2a, Sma, pa);
  EPI(acc01, rl0, colL1, S1b, S2b, Smb, pb);
  EPI(acc10, rl1, colL0, S1c, S2c, Smc, pc);
  EPI(acc11, rl1, colL1, S1d, S2d, Smd, pd);

  const float S1 = (S1a + S1b) + (S1c + S1d);
  const float S2 = (S2a + S2b) + (S2c + S2d);
  const float Sm = (Sma + Smb) + (Smc + Smd);
  const float pp = (pa * pb) * (pc * pd);         // <= 2^64, in range
  float loss = 0.5f * (S1 + S2) - Sm + __builtin_amdgcn_logf(pp);

#pragma unroll
  for (int off = 32; off > 0; off >>= 1) loss += __shfl_down(loss, off, 64);
  if (lane == 0) sPart[wid] = loss;
  __syncthreads();
  if (tid == 0) {
    const float s = (sPart[0] + sPart[1]) + (sPart[2] + sPart[3]);
    atomicAdd(out, s * (0.6931471805599453f / (float)N_TOK));
  }
}

extern "C" void kernel_launch(void* const* d_in, const int* in_sizes, int n_in,
                              void* d_out, int out_size, void* d_ws, size_t ws_size,
                              hipStream_t stream) {
  const float* a  = (const float*)d_in[0];
  const float* b  = (const float*)d_in[1];
  const int*   la = (const int*)d_in[2];
  const int*   lb = (const int*)d_in[3];
  const float* sc = (const float*)d_in[4];
  const float* bi = (const float*)d_in[5];
  float* out = (float*)d_out;

  unsigned char* wa = (unsigned char*)d_ws;          // fp8 A', 8 MB
  unsigned char* wb = wa + (size_t)N_TOK * D_K;      // fp8 B', 8 MB

  convert_perm_kernel<<<512, 256, 0, stream>>>(a, b, wa, wb, out);
  const int grid = (N_TOK / NB) * (N_TOK / NB);      // 4096
  sigc_kernel<<<grid, 256, 0, stream>>>(wa, wb, la, lb, sc, bi, out);
}